// Round 9
// baseline (17.646 us; speedup 1.0000x reference)
//
#include <hip/hip_runtime.h>

namespace {

constexpr int IMG = 192;
constexpr int OX = 95, OY = 95;
constexpr int NPB = OX * OY;            // 9025 patches / image
constexpr int BATCH = 128;
constexpr int IP = 48, JPC = 48;        // 2x2-patch blocks per image
constexpr int PERIMG = IP * JPC;        // 2304 threads / image
constexpr int TOTAL = BATCH * PERIMG;   // 294,912
constexpr int NWG = TOTAL / 256;        // 1152
constexpr int CHUNK = NWG / 8;          // 144

using f32x4 = __attribute__((ext_vector_type(4))) float;

__device__ __forceinline__ float2 cmul(float2 a, float2 b) {
    return make_float2(a.x*b.x - a.y*b.y, a.x*b.y + a.y*b.x);
}

// Bloch chain: RZ(t0) RY(t1) RZ(t2) RY(t3) RZ(t4) on (1,0,0); full-angle sincos in.
__device__ __forceinline__ void bloch_chain(
    float s0, float c0, float s1, float c1, float s2, float c2,
    float s3, float c3, float s4, float c4,
    float& z, float& cx, float& cy)
{
    float x1  = c0 * c1;
    float z1n = c0 * s1;                    // z1 = -z1n
    float x2 = x1*c2 - s0*s2;
    float y2 = x1*s2 + s0*c2;
    float x3 = x2*c3 - z1n*s3;
    float z3 = -z1n*c3 - x2*s3;
    cx = x3*c4 - y2*s4;
    cy = x3*s4 + y2*c4;
    z  = z3;
}

// sn/cs: 4 rows x 6 cols of full-angle sincos for this patch band; o = 0 or 2.
__device__ __forceinline__ f32x4 patch_ev(
    const float (*sn)[6], const float (*cs)[6], int o,
    const float wsc[36])
{
    float z[3], cqx[4], cqy[4];
    bloch_chain(sn[0][o+0],cs[0][o+0], sn[0][o+1],cs[0][o+1], sn[0][o+2],cs[0][o+2],
                sn[0][o+3],cs[0][o+3], sn[1][o+0],cs[1][o+0], z[0], cqx[0], cqy[0]);
    bloch_chain(sn[1][o+1],cs[1][o+1], sn[1][o+2],cs[1][o+2], sn[1][o+3],cs[1][o+3],
                sn[2][o+0],cs[2][o+0], sn[2][o+1],cs[2][o+1], z[1], cqx[1], cqy[1]);
    bloch_chain(sn[2][o+2],cs[2][o+2], sn[2][o+3],cs[2][o+3], sn[3][o+0],cs[3][o+0],
                sn[3][o+1],cs[3][o+1], sn[3][o+2],cs[3][o+2], z[2], cqx[2], cqy[2]);
    cqx[3] = cs[3][o+3];  cqy[3] = sn[3][o+3];   // qubit 3: z = 0 exactly

    float zz = z[0] * z[2];
    f32x4 ev;
    {   // q0: T = P0 + z1*R0
        float Tx = fmaf(z[1], wsc[4], wsc[0]);
        float Ty = fmaf(z[1], wsc[5], wsc[1]);
        float t = cqx[0]*Tx - cqy[0]*Ty;
        ev.x = fmaf(wsc[32], z[0], -t);
    }
    {   // q1: T = P1 + z0*Q1 + z2*R1 + zz*S1
        float Tx = fmaf(zz, wsc[8+6], fmaf(z[2], wsc[8+4], fmaf(z[0], wsc[8+2], wsc[8+0])));
        float Ty = fmaf(zz, wsc[8+7], fmaf(z[2], wsc[8+5], fmaf(z[0], wsc[8+3], wsc[8+1])));
        float t = cqx[1]*Tx - cqy[1]*Ty;
        ev.y = fmaf(wsc[33], z[1], -t);
    }
    {   // q2: T = P2 + z1*Q2
        float Tx = fmaf(z[1], wsc[16+2], wsc[16+0]);
        float Ty = fmaf(z[1], wsc[16+3], wsc[16+1]);
        float t = cqx[2]*Tx - cqy[2]*Ty;
        ev.z = fmaf(wsc[34], z[2], -t);
    }
    {   // q3: T = P3 + z2*Q3 + z0*R3 + zz*S3; K2 term vanishes (z3=0)
        float Tx = fmaf(zz, wsc[24+6], fmaf(z[0], wsc[24+4], fmaf(z[2], wsc[24+2], wsc[24+0])));
        float Ty = fmaf(zz, wsc[24+7], fmaf(z[0], wsc[24+5], fmaf(z[2], wsc[24+3], wsc[24+1])));
        ev.w = fmaf(-cqx[3], Tx, cqy[3]*Ty);
    }
    return ev;
}

__global__ __launch_bounds__(256) void quanv_kernel(
    const float* __restrict__ X, const float* __restrict__ W,
    float* __restrict__ out)
{
    int orig = blockIdx.x;
    int wg = (orig & 7) * CHUNK + (orig >> 3);   // XCD-chunked swizzle
    int tid = wg * 256 + threadIdx.x;
    int b  = tid / PERIMG;
    int r  = tid - b * PERIMG;
    int i  = r / JPC;                            // block row (px = 2i, 2i+1)
    int j  = r - i * JPC;                        // block col (py = 2j, 2j+1)
    const bool hasX = (i < IP - 1);
    const bool hasY = (j < JPC - 1);

    const float* img = X + (size_t)b * (IMG * IMG) + 4 * j;
    const int c45 = hasY ? 4 : 0;

    // issue all 6 row loads up front
    float raw[6][6];
#pragma unroll
    for (int di = 0; di < 6; ++di) {
        int rr = 4 * i + di; if (rr > IMG - 1) rr = IMG - 1;
        const float* rp = img + rr * IMG;
        float4 v  = *reinterpret_cast<const float4*>(rp);
        float2 w2 = *reinterpret_cast<const float2*>(rp + c45);
        raw[di][0] = v.x; raw[di][1] = v.y; raw[di][2] = v.z; raw[di][3] = v.w;
        raw[di][4] = w2.x; raw[di][5] = w2.y;
    }

    // weight-derived constants (uniform; amortized over 4 patches)
    float wsc[36];
    {
        float cw[4], sw[4], ehx[4], ehy[4], S4[4];
#pragma unroll
        for (int k = 0; k < 4; ++k) {
            float sh, ch, sry, cry;
            __sincosf(0.5f * W[k], &sh, &ch);
            __sincosf(W[4 + k], &sry, &cry);
            cw[k] = ch*ch - sh*sh;  sw[k] = 2.f*ch*sh;
            ehx[k] = ch;  ehy[k] = -sh;
            S4[k] = 0.25f * sry;
            wsc[32 + k] = cry;
        }
#pragma unroll
        for (int q = 0; q < 4; ++q) {
            int qm = (q + 3) & 3;
            float2 AC = make_float2(1.f + cw[qm],  sw[qm]);
            float2 BC = make_float2(1.f - cw[qm], -sw[qm]);
            float2 AT = make_float2(1.f + cw[q],   sw[q]);
            float2 BT = make_float2(1.f - cw[q],  -sw[q]);
            float2 G  = make_float2(S4[q]*ehx[q], S4[q]*ehy[q]);
            float2 P = cmul(cmul(G, AC), AT);
            float2 Q = cmul(cmul(G, BC), AT);
            float2 R = cmul(cmul(G, AC), BT);
            float2 S = cmul(cmul(G, BC), BT);
            wsc[q*8+0] = P.x; wsc[q*8+1] = P.y;
            wsc[q*8+2] = Q.x; wsc[q*8+3] = Q.y;
            wsc[q*8+4] = R.x; wsc[q*8+5] = R.y;
            wsc[q*8+6] = S.x; wsc[q*8+7] = S.y;
        }
    }

    f32x4* o4 = reinterpret_cast<f32x4*>(out) + (size_t)b * NPB + (2 * i) * OY + 2 * j;

    // --- band 1: pixel rows 0..3 -> top two patches ---
    float sn[6][6], cs[6][6];
#pragma unroll
    for (int di = 0; di < 4; ++di)
#pragma unroll
        for (int cc = 0; cc < 6; ++cc)
            __sincosf(raw[di][cc], &sn[di][cc], &cs[di][cc]);

    // nontemporal: output is write-once, keep it out of L2 so input rows stay cached
    __builtin_nontemporal_store(patch_ev(sn + 0, cs + 0, 0, wsc), o4 + 0);
    if (hasY) __builtin_nontemporal_store(patch_ev(sn + 0, cs + 0, 2, wsc), o4 + 1);

    // --- band 2: pixel rows 4..5 -> bottom two patches (rows 2..5) ---
    if (hasX) {
#pragma unroll
        for (int di = 4; di < 6; ++di)
#pragma unroll
            for (int cc = 0; cc < 6; ++cc)
                __sincosf(raw[di][cc], &sn[di][cc], &cs[di][cc]);

        __builtin_nontemporal_store(patch_ev(sn + 2, cs + 2, 0, wsc), o4 + OY);
        if (hasY) __builtin_nontemporal_store(patch_ev(sn + 2, cs + 2, 2, wsc), o4 + OY + 1);
    }
}

} // namespace

extern "C" void kernel_launch(void* const* d_in, const int* in_sizes, int n_in,
                              void* d_out, int out_size, void* d_ws, size_t ws_size,
                              hipStream_t stream) {
    const float* X = (const float*)d_in[0];
    const float* W = (const float*)d_in[1];
    float* out = (float*)d_out;
    quanv_kernel<<<NWG, 256, 0, stream>>>(X, W, out);
}

// Round 10
// 14.536 us; speedup vs baseline: 1.2139x; 1.2139x over previous
//
#include <hip/hip_runtime.h>

namespace {

constexpr int IMG = 192;
constexpr int OX = 95, OY = 95;
constexpr int NPB = OX * OY;            // 9025 patches / image
constexpr int BATCH = 128;
constexpr int IP = 48, JPC = 48;        // 2x2-patch blocks per image: 48x48
constexpr int PERIMG = IP * JPC;        // 2304 threads / image
constexpr int TOTAL = BATCH * PERIMG;   // 294,912
constexpr int NWG = TOTAL / 256;        // 1152
constexpr int CHUNK = NWG / 8;          // 144

__device__ __forceinline__ float2 cmul(float2 a, float2 b) {
    return make_float2(a.x*b.x - a.y*b.y, a.x*b.y + a.y*b.x);
}

// Bloch chain: RZ(t0) RY(t1) RZ(t2) RY(t3) RZ(t4) on (1,0,0); full-angle sincos in.
__device__ __forceinline__ void bloch_chain(
    float s0, float c0, float s1, float c1, float s2, float c2,
    float s3, float c3, float s4, float c4,
    float& z, float& cx, float& cy)
{
    float x1  = c0 * c1;
    float z1n = c0 * s1;                    // z1 = -z1n
    float x2 = x1*c2 - s0*s2;
    float y2 = x1*s2 + s0*c2;
    float x3 = x2*c3 - z1n*s3;
    float z3 = -z1n*c3 - x2*s3;
    cx = x3*c4 - y2*s4;
    cy = x3*s4 + y2*c4;
    z  = z3;
}

// sn/cs point at the patch's top pixel row (4 rows used); o = col offset (0 or 2).
__device__ __forceinline__ float4 patch_ev(
    const float (*sn)[6], const float (*cs)[6], int o,
    const float wsc[36])
{
    float z[3], cqx[4], cqy[4];
    bloch_chain(sn[0][o+0],cs[0][o+0], sn[0][o+1],cs[0][o+1], sn[0][o+2],cs[0][o+2],
                sn[0][o+3],cs[0][o+3], sn[1][o+0],cs[1][o+0], z[0], cqx[0], cqy[0]);
    bloch_chain(sn[1][o+1],cs[1][o+1], sn[1][o+2],cs[1][o+2], sn[1][o+3],cs[1][o+3],
                sn[2][o+0],cs[2][o+0], sn[2][o+1],cs[2][o+1], z[1], cqx[1], cqy[1]);
    bloch_chain(sn[2][o+2],cs[2][o+2], sn[2][o+3],cs[2][o+3], sn[3][o+0],cs[3][o+0],
                sn[3][o+1],cs[3][o+1], sn[3][o+2],cs[3][o+2], z[2], cqx[2], cqy[2]);
    cqx[3] = cs[3][o+3];  cqy[3] = sn[3][o+3];   // qubit 3: z = 0 exactly

    float zz = z[0] * z[2];
    float ev[4];
    {   // q0: T = P0 + z1*R0
        float Tx = fmaf(z[1], wsc[4], wsc[0]);
        float Ty = fmaf(z[1], wsc[5], wsc[1]);
        float t = cqx[0]*Tx - cqy[0]*Ty;
        ev[0] = fmaf(wsc[32], z[0], -t);
    }
    {   // q1: T = P1 + z0*Q1 + z2*R1 + zz*S1
        float Tx = fmaf(zz, wsc[8+6], fmaf(z[2], wsc[8+4], fmaf(z[0], wsc[8+2], wsc[8+0])));
        float Ty = fmaf(zz, wsc[8+7], fmaf(z[2], wsc[8+5], fmaf(z[0], wsc[8+3], wsc[8+1])));
        float t = cqx[1]*Tx - cqy[1]*Ty;
        ev[1] = fmaf(wsc[33], z[1], -t);
    }
    {   // q2: T = P2 + z1*Q2
        float Tx = fmaf(z[1], wsc[16+2], wsc[16+0]);
        float Ty = fmaf(z[1], wsc[16+3], wsc[16+1]);
        float t = cqx[2]*Tx - cqy[2]*Ty;
        ev[2] = fmaf(wsc[34], z[2], -t);
    }
    {   // q3: T = P3 + z2*Q3 + z0*R3 + zz*S3; K2 term vanishes (z3=0)
        float Tx = fmaf(zz, wsc[24+6], fmaf(z[0], wsc[24+4], fmaf(z[2], wsc[24+2], wsc[24+0])));
        float Ty = fmaf(zz, wsc[24+7], fmaf(z[0], wsc[24+5], fmaf(z[2], wsc[24+3], wsc[24+1])));
        ev[3] = fmaf(-cqx[3], Tx, cqy[3]*Ty);
    }
    return make_float4(ev[0], ev[1], ev[2], ev[3]);
}

__global__ __launch_bounds__(256) void quanv_kernel(
    const float* __restrict__ X, const float* __restrict__ W,
    float* __restrict__ out)
{
    int orig = blockIdx.x;
    int wg = (orig & 7) * CHUNK + (orig >> 3);   // XCD-chunked swizzle
    int tid = wg * 256 + threadIdx.x;
    int b  = tid / PERIMG;
    int r  = tid - b * PERIMG;
    int i  = r / JPC;                            // 2x2 block row (px = 2i, 2i+1)
    int j  = r - i * JPC;                        // 2x2 block col (py = 2j, 2j+1)
    const bool hasX = (i < IP - 1);              // px = 95 invalid when i == 47
    const bool hasY = (j < JPC - 1);             // py = 95 invalid when j == 47

    const float* img = X + (size_t)b * (IMG * IMG) + 4 * j;
    const int c45 = hasY ? 4 : 0;

    // 6x6 pixel block, sincos computed in place
    float sn[6][6], cs[6][6];
#pragma unroll
    for (int di = 0; di < 6; ++di) {
        int rr = 4 * i + di; if (rr > IMG - 1) rr = IMG - 1;
        const float* rp = img + rr * IMG;
        float4 v  = *reinterpret_cast<const float4*>(rp);
        float2 w2 = *reinterpret_cast<const float2*>(rp + c45);
        __sincosf(v.x,  &sn[di][0], &cs[di][0]);
        __sincosf(v.y,  &sn[di][1], &cs[di][1]);
        __sincosf(v.z,  &sn[di][2], &cs[di][2]);
        __sincosf(v.w,  &sn[di][3], &cs[di][3]);
        __sincosf(w2.x, &sn[di][4], &cs[di][4]);
        __sincosf(w2.y, &sn[di][5], &cs[di][5]);
    }

    // weight-derived constants, per-thread (uniform; amortized over 4 patches)
    float wsc[36];
    {
        float cw[4], sw[4], ehx[4], ehy[4], S4[4];
#pragma unroll
        for (int k = 0; k < 4; ++k) {
            float sh, ch, sry, cry;
            __sincosf(0.5f * W[k], &sh, &ch);
            __sincosf(W[4 + k], &sry, &cry);
            cw[k] = ch*ch - sh*sh;  sw[k] = 2.f*ch*sh;
            ehx[k] = ch;  ehy[k] = -sh;          // e^{-i w/2}
            S4[k] = 0.25f * sry;
            wsc[32 + k] = cry;                   // K2
        }
#pragma unroll
        for (int q = 0; q < 4; ++q) {
            int qm = (q + 3) & 3;
            float2 AC = make_float2(1.f + cw[qm],  sw[qm]);
            float2 BC = make_float2(1.f - cw[qm], -sw[qm]);
            float2 AT = make_float2(1.f + cw[q],   sw[q]);
            float2 BT = make_float2(1.f - cw[q],  -sw[q]);
            float2 G  = make_float2(S4[q]*ehx[q], S4[q]*ehy[q]);
            float2 P = cmul(cmul(G, AC), AT);
            float2 Q = cmul(cmul(G, BC), AT);
            float2 R = cmul(cmul(G, AC), BT);
            float2 S = cmul(cmul(G, BC), BT);
            wsc[q*8+0] = P.x; wsc[q*8+1] = P.y;
            wsc[q*8+2] = Q.x; wsc[q*8+3] = Q.y;
            wsc[q*8+4] = R.x; wsc[q*8+5] = R.y;
            wsc[q*8+6] = S.x; wsc[q*8+7] = S.y;
        }
    }

    float4* o4 = reinterpret_cast<float4*>(out) + (size_t)b * NPB + (2 * i) * OY + 2 * j;

    // top patch row (pixel rows 0..3), then bottom (rows 2..5)
    float4 e00 = patch_ev(sn + 0, cs + 0, 0, wsc);
    o4[0] = e00;
    if (hasY) {
        float4 e01 = patch_ev(sn + 0, cs + 0, 2, wsc);
        o4[1] = e01;
    }
    if (hasX) {
        float4 e10 = patch_ev(sn + 2, cs + 2, 0, wsc);
        o4[OY] = e10;
        if (hasY) {
            float4 e11 = patch_ev(sn + 2, cs + 2, 2, wsc);
            o4[OY + 1] = e11;
        }
    }
}

} // namespace

extern "C" void kernel_launch(void* const* d_in, const int* in_sizes, int n_in,
                              void* d_out, int out_size, void* d_ws, size_t ws_size,
                              hipStream_t stream) {
    const float* X = (const float*)d_in[0];
    const float* W = (const float*)d_in[1];
    float* out = (float*)d_out;
    quanv_kernel<<<NWG, 256, 0, stream>>>(X, W, out);
}